// Round 8
// baseline (767.623 us; speedup 1.0000x reference)
//
#include <hip/hip_runtime.h>
#include <cstdint>

#define B_ 128
#define T_ 1024
#define D_ 256
#define U_ 48

typedef float v2f __attribute__((ext_vector_type(2)));

// Guaranteed packed fp32 add (2 IEEE adds, bit-identical to scalar v_add_f32).
__device__ __forceinline__ v2f pk_add(v2f a, v2f b) {
    v2f d;
    asm("v_pk_add_f32 %0, %1, %2" : "=v"(d) : "v"(a), "v"(b));
    return d;
}
// Guaranteed 3-input max (exact, same result as two v_max_f32).
__device__ __forceinline__ float max3f(float a, float b, float c) {
    float d;
    asm("v_max3_f32 %0, %1, %2, %3" : "=v"(d) : "v"(a), "v"(b), "v"(c));
    return d;
}

// ---------------------------------------------------------------------------
// K1: logits (unchanged).
// ---------------------------------------------------------------------------
__global__ __launch_bounds__(256, 1) void k_logits(const float* __restrict__ x,
                                                   const float* __restrict__ kern,
                                                   const float* __restrict__ bias,
                                                   float* __restrict__ logits) {
    __shared__ float K[D_ * U_];   // 48 KB
    __shared__ float bsh[U_];
    const int tid = threadIdx.x;
    for (int i = tid; i < D_ * U_; i += 256) K[i] = kern[i];
    if (tid < U_) bsh[tid] = bias[tid];
    __syncthreads();

    const long row0 = (long)blockIdx.x * 256 + tid;      // 0..65535
    const long row1 = row0 + (long)B_ * T_ / 2;          // +65536
    const float4* xr0 = (const float4*)(x + row0 * D_);
    const float4* xr1 = (const float4*)(x + row1 * D_);

    float a0[U_], a1[U_];
#pragma unroll
    for (int u = 0; u < U_; ++u) { a0[u] = 0.0f; a1[u] = 0.0f; }

#pragma unroll 1
    for (int blk = 0; blk < D_ / 32; ++blk) {            // 8 chunks of 128 B
        float4 xa[8], xb[8];
#pragma unroll
        for (int i = 0; i < 8; ++i) xa[i] = xr0[blk * 8 + i];
#pragma unroll
        for (int i = 0; i < 8; ++i) xb[i] = xr1[blk * 8 + i];

#pragma unroll
        for (int i = 0; i < 8; ++i) {
            const int d4 = blk * 8 + i;
            const float xc0[4] = {xa[i].x, xa[i].y, xa[i].z, xa[i].w};
            const float xc1[4] = {xb[i].x, xb[i].y, xb[i].z, xb[i].w};
#pragma unroll
            for (int c = 0; c < 4; ++c) {
                const float4* kp = (const float4*)&K[(d4 * 4 + c) * U_];
                const float s0 = xc0[c], s1 = xc1[c];
#pragma unroll
                for (int u4 = 0; u4 < U_ / 4; ++u4) {
                    float4 kv = kp[u4];
                    a0[u4*4+0] += s0 * kv.x;  a1[u4*4+0] += s1 * kv.x;
                    a0[u4*4+1] += s0 * kv.y;  a1[u4*4+1] += s1 * kv.y;
                    a0[u4*4+2] += s0 * kv.z;  a1[u4*4+2] += s1 * kv.z;
                    a0[u4*4+3] += s0 * kv.w;  a1[u4*4+3] += s1 * kv.w;
                }
            }
        }
    }

    float4* o0 = (float4*)(logits + row0 * U_);
    float4* o1 = (float4*)(logits + row1 * U_);
#pragma unroll
    for (int i = 0; i < U_ / 4; ++i) {
        float4 v0, v1;
        v0.x = a0[i*4+0] + bsh[i*4+0];  v1.x = a1[i*4+0] + bsh[i*4+0];
        v0.y = a0[i*4+1] + bsh[i*4+1];  v1.y = a1[i*4+1] + bsh[i*4+1];
        v0.z = a0[i*4+2] + bsh[i*4+2];  v1.z = a1[i*4+2] + bsh[i*4+2];
        v0.w = a0[i*4+3] + bsh[i*4+3];  v1.w = a1[i*4+3] + bsh[i*4+3];
        o0[i] = v0;
        o1[i] = v1;
    }
}

// ---------------------------------------------------------------------------
// Max-plus body (R2-measured best): 12x ds_read_b128 uniform broadcast +
// 24x v_pk_add_f32 + 24x v_max3_f32 tree 48->16->6->2->1. Exact.
// ---------------------------------------------------------------------------
__device__ __forceinline__ float step_max_lds(const float4* sb, const v2f* tc2) {
    float4 s[12];
#pragma unroll
    for (int k = 0; k < 12; ++k) s[k] = sb[k];
    float cf[48];
#pragma unroll
    for (int k = 0; k < 12; ++k) {
        v2f lo, hi;
        lo.x = s[k].x; lo.y = s[k].y;
        hi.x = s[k].z; hi.y = s[k].w;
        v2f r0 = pk_add(lo, tc2[2 * k + 0]);
        v2f r1 = pk_add(hi, tc2[2 * k + 1]);
        cf[4*k+0] = r0.x; cf[4*k+1] = r0.y;
        cf[4*k+2] = r1.x; cf[4*k+3] = r1.y;
    }
    float t1[16];
#pragma unroll
    for (int i = 0; i < 16; ++i) t1[i] = max3f(cf[3*i], cf[3*i+1], cf[3*i+2]);
    float t2[6];
#pragma unroll
    for (int i = 0; i < 5; ++i) t2[i] = max3f(t1[3*i], t1[3*i+1], t1[3*i+2]);
    t2[5] = t1[15];
    const float a = max3f(t2[0], t2[1], t2[2]);
    const float b = max3f(t2[3], t2[4], t2[5]);
    return fmaxf(a, b);
}

// ---------------------------------------------------------------------------
// K2 (fused, R8-fix): wave 0 = chain with R2-exact compile-time parity sbuf
// (the ring is write-only for the chain: rb + imm offsets, no serial runtime
// addressing on the read path). wave 1 = bp argmax one 32-row batch behind,
// reading the ring half the chain is NOT writing. Epilogue = R7-verified
// in-block blocked-composition backtrace. One barrier per batch.
// NOTE: the final chain group prefetches logits rows 1024..1031 (b=127 reads
// <=1536 B past the logits buffer) -- ws is ~56 MB, logits 24 MB, so the
// over-read stays inside d_ws (values never consumed).
// ---------------------------------------------------------------------------
#define RING 64

__global__ __launch_bounds__(128, 1) void k_fused(const float* __restrict__ trans,
                                                  const float* __restrict__ logits,
                                                  float* __restrict__ out) {
    __shared__ __align__(16) float ringf[RING * U_];   // 12288 B: delta ring
    __shared__ __align__(16) float sbf[2 * U_];        // parity double buffer
    __shared__ unsigned char bpl[1024 * U_];           // 49152 B (row 1023 id)
    __shared__ unsigned char gmap[32 * U_];            // 1536 B
    __shared__ unsigned char eIn[32];
    __shared__ int Ash;

    const int tid = threadIdx.x;
    const int wid = tid >> 6;                     // 0 = chain, 1 = bp
    const int lane = tid & 63;
    const int b = blockIdx.x;
    const int u = (lane < U_) ? lane : (U_ - 1);

    const float* lin = logits + (long)b * T_ * U_;

    // chain-wave state
    v2f tc2[U_ / 2];
    float state = 0.0f, pf[8];
    const float* lp = lin + 9 * U_ + u;
    // bp-wave state
    float tc[U_];

    if (wid == 0) {
#pragma unroll
        for (int v = 0; v < U_; v += 2) {
            tc2[v / 2].x = trans[v * U_ + u];
            tc2[v / 2].y = trans[(v + 1) * U_ + u];
        }
        state = lin[u];                           // delta_0
        ringf[u] = state;                         // slot 0 (dup benign)
        sbf[u] = state;                           // parity 0
#pragma unroll
        for (int i = 0; i < 8; ++i) pf[i] = lin[(1 + i) * U_ + u];  // rows 1..8

        // ---- prologue: t = 1..24 (3 groups of 8), R2 parity (read j&1) ----
        float* rp = ringf + U_;                   // ring row 1
#pragma unroll 1
        for (int g = 0; g < 3; ++g) {
#pragma unroll
            for (int j = 0; j < 8; ++j) {
                const float logit = pf[j];
                pf[j] = lp[j * U_];
                const float m = step_max_lds((const float4*)(sbf + (j & 1) * U_), tc2);
                state = logit + m;
                sbf[((j & 1) ^ 1) * U_ + u] = state;
                rp[j * U_ + u] = state;
            }
            lp += 8 * U_;
            rp += 8 * U_;
        }
        // ---- singles: t = 25..31 ----
#pragma unroll
        for (int j = 0; j < 7; ++j) {
            const float logit = pf[j];
            pf[j] = lp[j * U_];
            const float m = step_max_lds((const float4*)(sbf + (j & 1) * U_), tc2);
            state = logit + m;
            sbf[((j & 1) ^ 1) * U_ + u] = state;
            rp[j * U_ + u] = state;
        }
        lp += 7 * U_;
        // pf state now: pf[7]=row32, pf[0..6]=rows 33..39; lp = row 40 base.
    } else {
#pragma unroll
        for (int v = 0; v < U_; ++v) tc[v] = trans[v * U_ + u];
    }
    __syncthreads();                              // batch 0 (slots 0..31) visible

    // ---- main: chain batch kb (t = 32kb..32kb+31), bp batch kb-1 ----
#pragma unroll 1
    for (int kb = 1; kb <= 32; ++kb) {
        if (wid == 0 && kb <= 31) {
            float* rb = ringf + (kb & 1) * (32 * U_);
#pragma unroll 1
            for (int jj = 0; jj < 4; ++jj) {
#pragma unroll
                for (int s = 0; s < 8; ++s) {     // t = 32kb+8jj+s
                    const int idx = (7 + s) & 7;  // consume order 7,0,..,6
                    const float logit = pf[idx];
                    pf[idx] = lp[s * U_];
                    const float m = step_max_lds(
                        (const float4*)(sbf + ((s + 1) & 1) * U_), tc2);
                    state = logit + m;
                    sbf[(s & 1) * U_ + u] = state;
                    rb[s * U_ + u] = state;
                }
                lp += 8 * U_;
                rb += 8 * U_;
            }
        }
        if (wid == 1) {
            const int kbp = kb - 1;               // 0..31
            const int r0 = kbp * 32;
            const int nr = (kbp == 31) ? 31 : 32; // skip row 1023
            const float* rbase = ringf + (kbp & 1) * (32 * U_);
#pragma unroll 1
            for (int i = 0; i < nr; ++i) {
                const float4* sb4 = (const float4*)(rbase + i * U_);
                float best = -3.4e38f;
                int bi = 0;
#pragma unroll
                for (int k = 0; k < U_ / 4; ++k) {
                    float4 s = sb4[k];            // uniform broadcast read
                    float c0 = s.x + tc[4*k+0];
                    float c1 = s.y + tc[4*k+1];
                    float c2 = s.z + tc[4*k+2];
                    float c3 = s.w + tc[4*k+3];
                    bi = (c0 > best) ? 4*k+0 : bi;  best = fmaxf(best, c0);
                    bi = (c1 > best) ? 4*k+1 : bi;  best = fmaxf(best, c1);
                    bi = (c2 > best) ? 4*k+2 : bi;  best = fmaxf(best, c2);
                    bi = (c3 > best) ? 4*k+3 : bi;  best = fmaxf(best, c3);
                }
                bpl[(r0 + i) * U_ + u] = (unsigned char)bi;   // dup benign
            }
        }
        __syncthreads();
    }

    // ---- epilogue: in-block backtrace (R7-verified) ----
    if (tid < U_) bpl[1023 * U_ + tid] = (unsigned char)tid;   // identity row
    if (wid == 0) {                               // argmax of delta row 1023
        float v = (lane < U_) ? ringf[63 * U_ + lane] : -3.4e38f;
        int idx = (lane < U_) ? lane : 64;
#pragma unroll
        for (int off = 32; off >= 1; off >>= 1) {
            const float ov = __shfl_xor(v, off);
            const int oi = __shfl_xor(idx, off);
            if (ov > v || (ov == v && oi < idx)) { v = ov; idx = oi; }
        }
        if (lane == 0) Ash = idx;
    }
    __syncthreads();

    // Phase A: 1536 (block, entry-tag) chases, 12 per thread, interleaved.
    int ik[12], ek[12], ck[12];
#pragma unroll
    for (int k = 0; k < 12; ++k) {
        const int tau = tid + k * 128;
        ik[k] = tau / U_;                         // block 0..31
        ek[k] = tau - ik[k] * U_;                 // entry tag 0..47
        ck[k] = ek[k];
    }
#pragma unroll
    for (int h = 0; h < 32; ++h) {
#pragma unroll
        for (int k = 0; k < 12; ++k) {
            const int r = ik[k] * 32 + (31 - h);
            ck[k] = bpl[r * U_ + ck[k]];
        }
    }
#pragma unroll
    for (int k = 0; k < 12; ++k) gmap[ik[k] * U_ + ek[k]] = (unsigned char)ck[k];
    __syncthreads();

    // Phase B: serial composition over 32 block maps.
    if (tid == 0) {
        int cur = Ash;
        eIn[31] = (unsigned char)cur;
#pragma unroll 1
        for (int i = 31; i >= 1; --i) {
            cur = gmap[i * U_ + cur];
            eIn[i - 1] = (unsigned char)cur;
        }
    }
    __syncthreads();

    // Phase C: 32 parallel re-chases, tags straight to global.
    float* o = out + (long)b * T_;
    if (tid < 32) {
        int cur = eIn[tid];
#pragma unroll
        for (int h = 0; h < 32; ++h) {
            const int r = tid * 32 + (31 - h);
            cur = bpl[r * U_ + cur];
            o[r] = (float)cur;
        }
    }
}

// ---------------------------------------------------------------------------
extern "C" void kernel_launch(void* const* d_in, const int* in_sizes, int n_in,
                              void* d_out, int out_size, void* d_ws, size_t ws_size,
                              hipStream_t stream) {
    const float* x     = (const float*)d_in[0];   // (B,T,D)
    const float* kern  = (const float*)d_in[1];   // (D,U)
    const float* bias  = (const float*)d_in[2];   // (U,)
    const float* trans = (const float*)d_in[3];   // (U,U)
    float* out = (float*)d_out;                   // (B,T) fp32 tags

    float* logits = (float*)d_ws;                 // 24 MB; ws has ample slack

    k_logits<<<(B_ * T_ / 2) / 256, 256, 0, stream>>>(x, kern, bias, logits);
    k_fused <<<B_, 128, 0, stream>>>(trans, logits, out);
}

// Round 9
// 737.699 us; speedup vs baseline: 1.0406x; 1.0406x over previous
//
#include <hip/hip_runtime.h>
#include <cstdint>

#define B_ 128
#define T_ 1024
#define D_ 256
#define U_ 48

typedef float v2f __attribute__((ext_vector_type(2)));

// Guaranteed packed fp32 add (2 IEEE adds, bit-identical to scalar v_add_f32).
__device__ __forceinline__ v2f pk_add(v2f a, v2f b) {
    v2f d;
    asm("v_pk_add_f32 %0, %1, %2" : "=v"(d) : "v"(a), "v"(b));
    return d;
}
// Guaranteed 3-input max (exact, same result as two v_max_f32).
__device__ __forceinline__ float max3f(float a, float b, float c) {
    float d;
    asm("v_max3_f32 %0, %1, %2, %3" : "=v"(d) : "v"(a), "v"(b), "v"(c));
    return d;
}

// ---------------------------------------------------------------------------
// K1: logits[row][u] = sum_d x[row][d]*kernel[d][u] + bias[u].
// R9: K/bias read DIRECTLY from global with wave-uniform addresses (loop
// indices only, no threadIdx) -> compiler scalarizes to s_load on the SMEM
// pipe, off the DS pipe entirely. Previous LDS-K version issued ~3072
// ds_read_b128/wave (~61 us DS-bound); VALU floor is ~20-25 us.
// x loads unchanged: own-line float4 x8 per chunk per row.
// ---------------------------------------------------------------------------
__global__ __launch_bounds__(256, 1) void k_logits(const float* __restrict__ x,
                                                   const float* __restrict__ kern,
                                                   const float* __restrict__ bias,
                                                   float* __restrict__ logits) {
    const int tid = threadIdx.x;
    const long row0 = (long)blockIdx.x * 256 + tid;      // 0..65535
    const long row1 = row0 + (long)B_ * T_ / 2;          // +65536
    const float4* xr0 = (const float4*)(x + row0 * D_);
    const float4* xr1 = (const float4*)(x + row1 * D_);

    float a0[U_], a1[U_];
#pragma unroll
    for (int u = 0; u < U_; ++u) { a0[u] = 0.0f; a1[u] = 0.0f; }

#pragma unroll 1
    for (int blk = 0; blk < D_ / 32; ++blk) {            // 8 chunks of 128 B
        float4 xa[8], xb[8];
#pragma unroll
        for (int i = 0; i < 8; ++i) xa[i] = xr0[blk * 8 + i];  // own line
#pragma unroll
        for (int i = 0; i < 8; ++i) xb[i] = xr1[blk * 8 + i];  // own line

#pragma unroll
        for (int i = 0; i < 8; ++i) {
            const int d4 = blk * 8 + i;
            const float xc0[4] = {xa[i].x, xa[i].y, xa[i].z, xa[i].w};
            const float xc1[4] = {xb[i].x, xb[i].y, xb[i].z, xb[i].w};
#pragma unroll
            for (int c = 0; c < 4; ++c) {
                // uniform address (no threadIdx) -> s_load broadcast
                const float4* kp = (const float4*)(kern + (d4 * 4 + c) * U_);
                const float s0 = xc0[c], s1 = xc1[c];
#pragma unroll
                for (int u4 = 0; u4 < U_ / 4; ++u4) {
                    float4 kv = kp[u4];
                    a0[u4*4+0] += s0 * kv.x;  a1[u4*4+0] += s1 * kv.x;
                    a0[u4*4+1] += s0 * kv.y;  a1[u4*4+1] += s1 * kv.y;
                    a0[u4*4+2] += s0 * kv.z;  a1[u4*4+2] += s1 * kv.z;
                    a0[u4*4+3] += s0 * kv.w;  a1[u4*4+3] += s1 * kv.w;
                }
            }
        }
    }

    float4* o0 = (float4*)(logits + row0 * U_);
    float4* o1 = (float4*)(logits + row1 * U_);
#pragma unroll
    for (int i = 0; i < U_ / 4; ++i) {
        // bias index uniform -> s_load
        const float b0 = bias[i*4+0], b1 = bias[i*4+1];
        const float b2 = bias[i*4+2], b3 = bias[i*4+3];
        float4 v0, v1;
        v0.x = a0[i*4+0] + b0;  v1.x = a1[i*4+0] + b0;
        v0.y = a0[i*4+1] + b1;  v1.y = a1[i*4+1] + b1;
        v0.z = a0[i*4+2] + b2;  v1.z = a1[i*4+2] + b2;
        v0.w = a0[i*4+3] + b3;  v1.w = a1[i*4+3] + b3;
        o0[i] = v0;
        o1[i] = v1;
    }
}

// ---------------------------------------------------------------------------
// Max-plus body (R2-measured best: 215.5 µs): LDS broadcast (12x ds_read_b128
// uniform) + 24x v_pk_add_f32 + 24x v_max3_f32 tree. Candidates are a single
// IEEE add of the same operands as ref; max reassociation exact. UNTOUCHED.
// ---------------------------------------------------------------------------
__device__ __forceinline__ float step_max_lds(const float4* sb, const v2f* tc2) {
    float4 s[12];
#pragma unroll
    for (int k = 0; k < 12; ++k) s[k] = sb[k];        // 12x ds_read_b128
    float cf[48];
#pragma unroll
    for (int k = 0; k < 12; ++k) {
        v2f lo, hi;
        lo.x = s[k].x; lo.y = s[k].y;
        hi.x = s[k].z; hi.y = s[k].w;
        v2f r0 = pk_add(lo, tc2[2 * k + 0]);
        v2f r1 = pk_add(hi, tc2[2 * k + 1]);
        cf[4*k+0] = r0.x; cf[4*k+1] = r0.y;
        cf[4*k+2] = r1.x; cf[4*k+3] = r1.y;
    }
    float t1[16];
#pragma unroll
    for (int i = 0; i < 16; ++i) t1[i] = max3f(cf[3*i], cf[3*i+1], cf[3*i+2]);
    float t2[6];
#pragma unroll
    for (int i = 0; i < 5; ++i) t2[i] = max3f(t1[3*i], t1[3*i+1], t1[3*i+2]);
    t2[5] = t1[15];
    const float a = max3f(t2[0], t2[1], t2[2]);
    const float b = max3f(t2[3], t2[4], t2[5]);
    return fmaxf(a, b);
}

// ---------------------------------------------------------------------------
// K2: Viterbi forward (R2/R6 structure verbatim — 215.4 µs measured).
// ---------------------------------------------------------------------------
__global__ __launch_bounds__(64, 1) void k_forward(const float* __restrict__ trans,
                                                   const float* __restrict__ logits,
                                                   float* __restrict__ delta) {
    __shared__ float4 sbuf[2][U_ / 4];    // parity double buffer, 2x48 floats
    const int lane = threadIdx.x;
    const int b = blockIdx.x;
    const int u = (lane < U_) ? lane : (U_ - 1);

    v2f tc2[U_ / 2];
#pragma unroll
    for (int v = 0; v < U_; v += 2) {
        tc2[v / 2].x = trans[v * U_ + u];
        tc2[v / 2].y = trans[(v + 1) * U_ + u];
    }

    const float* lin = logits + (long)b * T_ * U_;
    float* dout = delta + (long)b * T_ * U_;

    float state = lin[u];                 // delta_0 = logits row 0
    dout[u] = state;                      // dup-writes (lanes 48-63) benign
    ((float*)sbuf[0])[u] = state;         // t=0 parity 0

    float pf[8];
#pragma unroll
    for (int i = 0; i < 8; ++i) pf[i] = lin[(1 + i) * U_ + u];  // rows 1..8

    const float* lp = lin + 9 * U_ + u;   // prefetch base: row tb+8 for tb=1
    float* dp = dout + 1 * U_ + u;        // store base: row tb

#pragma unroll 1
    for (int g = 0; g < 127; ++g) {       // t = 1+8g .. 8+8g  (1..1016)
#pragma unroll
        for (int j = 0; j < 8; ++j) {
            const float logit = pf[j];
            pf[j] = lp[j * U_];                       // imm offset j*192 B

            const float4* sb = sbuf[j & 1];           // parity (t-1)&1 == j&1
            const float m = step_max_lds(sb, tc2);
            state = logit + m;                        // exact ref op order
            ((float*)sbuf[(j & 1) ^ 1])[u] = state;
            dp[j * U_] = state;                       // imm offset j*192 B
        }
        lp += 8 * U_;
        dp += 8 * U_;
    }

    // tail: t = 1017..1023 (7 steps); pf[0..6] hold rows 1017..1023
#pragma unroll
    for (int j = 0; j < 7; ++j) {
        const float logit = pf[j];
        const float4* sb = sbuf[j & 1];               // (t-1)=1016+j parity j&1
        const float m = step_max_lds(sb, tc2);
        state = logit + m;
        ((float*)sbuf[(j & 1) ^ 1])[u] = state;
        dp[j * U_] = state;
    }
}

// Fallback (in-place) variant if ws can't fit a second delta buffer.
__global__ __launch_bounds__(64, 1) void k_forward_inplace(const float* __restrict__ trans,
                                                           float* __restrict__ delta) {
    __shared__ float4 sbuf[2][U_ / 4];
    const int lane = threadIdx.x;
    const int b = blockIdx.x;
    const int u = (lane < U_) ? lane : (U_ - 1);

    v2f tc2[U_ / 2];
#pragma unroll
    for (int v = 0; v < U_; v += 2) {
        tc2[v / 2].x = trans[v * U_ + u];
        tc2[v / 2].y = trans[(v + 1) * U_ + u];
    }

    float* base = delta + (long)b * T_ * U_;
    float state = base[u];
    ((float*)sbuf[0])[u] = state;

#pragma unroll 1
    for (int t = 1; t < T_; ++t) {
        const float logit = base[(long)t * U_ + u];
        const float m = step_max_lds(sbuf[(t - 1) & 1], tc2);
        state = logit + m;
        ((float*)sbuf[t & 1])[u] = state;
        base[(long)t * U_ + u] = state;
    }
}

// ---------------------------------------------------------------------------
// K3: backpointers, R9: LDS staging removed. delta-row addresses are uniform
// per iteration (blockIdx/loop cursor only) -> s_load broadcast of the 48
// row values on the SMEM pipe; candidates/argmax identical scan order
// (ascending v, strict >) -> bit-identical bi.
// ---------------------------------------------------------------------------
#define BP_ROWS 32
__global__ __launch_bounds__(64, 1) void k_bp(const float* __restrict__ trans,
                                              const float* __restrict__ delta,
                                              unsigned char* __restrict__ bp) {
    const int lane = threadIdx.x;
    const int u = (lane < U_) ? lane : (U_ - 1);

    float tc[U_];
#pragma unroll
    for (int v = 0; v < U_; ++v) tc[v] = trans[v * U_ + u];

    const int NROW = B_ * (T_ - 1);       // 130944
    const int row0 = blockIdx.x * BP_ROWS;
    if (row0 >= NROW) return;

    int b = row0 / (T_ - 1);              // uniform, once per block
    int tm1 = row0 - b * (T_ - 1);        // (t-1) in 0..1022

#pragma unroll 1
    for (int i = 0; i < BP_ROWS; ++i) {
        const int row = row0 + i;
        if (row >= NROW) break;           // uniform guard

        const float* dr = delta + ((long)b * T_ + tm1) * U_;   // uniform addr
        float best = -3.4e38f;
        int bi = 0;
#pragma unroll
        for (int v = 0; v < U_; ++v) {
            const float c = dr[v] + tc[v];            // s_load + v_add
            bi = (c > best) ? v : bi;
            best = fmaxf(best, c);
        }
        bp[(long)row * U_ + u] = (unsigned char)bi;   // dup-writes benign

        ++tm1;
        if (tm1 == T_ - 1) { tm1 = 0; ++b; }
    }
}

// ---------------------------------------------------------------------------
// K4: backtrace (R6 blocked composition, verbatim — verified).
// ---------------------------------------------------------------------------
#define KB_ 32
#define NB_ 32
__global__ __launch_bounds__(256) void k_back(const float* __restrict__ delta,
                                              const unsigned char* __restrict__ bp,
                                              float* __restrict__ out) {
    __shared__ unsigned char bpl[1024 * U_];      // 49152 B (row 1023 = identity)
    __shared__ unsigned char gmap[NB_ * U_];      // 1536 B: gmap[i][e] = exit tag
    __shared__ unsigned char eIn[NB_];            // entry tag per block
    __shared__ float tags[T_];                    // 4 KB
    __shared__ int Ash;
    const int tid = threadIdx.x;
    const int b = blockIdx.x;

    // stage bp rows 0..1022 (12276 dwords), identity row 1023
    const uint32_t* src = (const uint32_t*)(bp + (long)b * (T_ - 1) * U_);
    uint32_t* dst = (uint32_t*)bpl;
    const int NW = (T_ - 1) * U_ / 4;             // 12276
    for (int i = tid; i < NW; i += 256) dst[i] = src[i];
    if (tid < U_) bpl[1023 * U_ + tid] = (unsigned char)tid;

    // wave-parallel argmax of final delta row (first wave only)
    if (tid < 64) {
        const int lane = tid;
        float v = (lane < U_) ? delta[((long)b * T_ + (T_ - 1)) * U_ + lane] : -3.4e38f;
        int idx = (lane < U_) ? lane : 64;
#pragma unroll
        for (int off = 32; off >= 1; off >>= 1) {
            const float ov = __shfl_xor(v, off);
            const int oi = __shfl_xor(idx, off);
            if (ov > v || (ov == v && oi < idx)) { v = ov; idx = oi; }
        }
        if (lane == 0) Ash = idx;
    }
    __syncthreads();

    // Phase A: 1536 tasks = 6 chains/thread, hop-major interleave.
    int ik[6], ek[6], ck[6];
#pragma unroll
    for (int k = 0; k < 6; ++k) {
        const int tau = tid + k * 256;
        ik[k] = tau / U_;                 // block 0..31
        ek[k] = tau - ik[k] * U_;         // entry tag 0..47
        ck[k] = ek[k];
    }
#pragma unroll
    for (int h = 0; h < KB_; ++h) {
#pragma unroll
        for (int k = 0; k < 6; ++k) {
            const int r = ik[k] * KB_ + (KB_ - 1 - h);   // hi down to lo
            ck[k] = bpl[r * U_ + ck[k]];
        }
    }
#pragma unroll
    for (int k = 0; k < 6; ++k) gmap[ik[k] * U_ + ek[k]] = (unsigned char)ck[k];
    __syncthreads();

    // Phase B: serial composition over block maps (31 dependent LDS reads).
    if (tid == 0) {
        int cur = Ash;
        eIn[NB_ - 1] = (unsigned char)cur;
#pragma unroll 1
        for (int i = NB_ - 1; i >= 1; --i) {
            cur = gmap[i * U_ + cur];
            eIn[i - 1] = (unsigned char)cur;
        }
    }
    __syncthreads();

    // Phase C: 32 parallel re-chases with known entry tags, emit all tags.
    if (tid < NB_) {
        const int i = tid;
        int cur = eIn[i];
#pragma unroll
        for (int h = 0; h < KB_; ++h) {
            const int r = i * KB_ + (KB_ - 1 - h);
            cur = bpl[r * U_ + cur];
            tags[r] = (float)cur;
        }
    }
    __syncthreads();

    float* o = out + (long)b * T_;
    for (int i = tid; i < T_; i += 256) o[i] = tags[i];
}

// ---------------------------------------------------------------------------
extern "C" void kernel_launch(void* const* d_in, const int* in_sizes, int n_in,
                              void* d_out, int out_size, void* d_ws, size_t ws_size,
                              hipStream_t stream) {
    const float* x     = (const float*)d_in[0];   // (B,T,D)
    const float* kern  = (const float*)d_in[1];   // (D,U)
    const float* bias  = (const float*)d_in[2];   // (U,)
    const float* trans = (const float*)d_in[3];   // (U,U)
    float* out = (float*)d_out;                   // (B,T) fp32 tags

    const size_t NBT = (size_t)B_ * T_ * U_ * sizeof(float);  // 25,165,824 B

    float* logits = (float*)d_ws;
    const bool two_buf = ws_size >= 2 * NBT + (size_t)B_ * T_ * U_;
    float* delta = two_buf ? (float*)((char*)d_ws + NBT) : logits;
    unsigned char* bp = (unsigned char*)d_ws + (two_buf ? 2 * NBT : NBT);

    const int NROW = B_ * (T_ - 1);
    const int bp_grid = (NROW + BP_ROWS - 1) / BP_ROWS;   // 4092

    k_logits<<<(B_ * T_ / 2) / 256, 256, 0, stream>>>(x, kern, bias, logits);
    if (two_buf)
        k_forward<<<B_, 64, 0, stream>>>(trans, logits, delta);
    else
        k_forward_inplace<<<B_, 64, 0, stream>>>(trans, logits);
    k_bp  <<<bp_grid, 64, 0, stream>>>(trans, delta, bp);
    k_back<<<B_, 256, 0, stream>>>(delta, bp, out);
}

// Round 10
// 499.185 us; speedup vs baseline: 1.5378x; 1.4778x over previous
//
#include <hip/hip_runtime.h>
#include <cstdint>

#define B_ 128
#define T_ 1024
#define D_ 256
#define U_ 48

typedef float v2f __attribute__((ext_vector_type(2)));

// Guaranteed packed fp32 add (2 IEEE adds, bit-identical to scalar v_add_f32).
__device__ __forceinline__ v2f pk_add(v2f a, v2f b) {
    v2f d;
    asm("v_pk_add_f32 %0, %1, %2" : "=v"(d) : "v"(a), "v"(b));
    return d;
}
// Guaranteed 3-input max (exact, same result as two v_max_f32).
__device__ __forceinline__ float max3f(float a, float b, float c) {
    float d;
    asm("v_max3_f32 %0, %1, %2, %3" : "=v"(d) : "v"(a), "v"(b), "v"(c));
    return d;
}

// ---------------------------------------------------------------------------
// K1: logits[row][u] = sum_d x[row][d]*kernel[d][u] + bias[u].
// R10: u-split 12/lane x 8 rows/lane. K stays in LDS (R9's global-K spilled:
// WRITE_SIZE 70MB scratch). DS issue per wave drops 12288 -> 768 b128
// (3 per d, shared by 8 rows) => DS/CU ~15 us vs ~60-100+. Lane l: ugroup
// l>>4 owns u [12*ug,12*ug+12), rowslot l&15 owns 8 rows. All acc indices
// compile-time (no scratch). d-ascending accumulation chain per (row,u),
// bias added once at end -> bit-identical to prior passing kernels.
// ---------------------------------------------------------------------------
__global__ __launch_bounds__(256, 1) void k_logits(const float* __restrict__ x,
                                                   const float* __restrict__ kern,
                                                   const float* __restrict__ bias,
                                                   float* __restrict__ logits) {
    __shared__ float K[D_ * U_];   // 48 KB
    __shared__ float bsh[U_];
    const int tid = threadIdx.x;
    for (int i = tid; i < D_ * U_; i += 256) K[i] = kern[i];
    if (tid < U_) bsh[tid] = bias[tid];
    __syncthreads();

    const int lane = tid & 63;
    const int wv = tid >> 6;              // wave 0..3
    const int ug = lane >> 4;             // u-group 0..3
    const int u0 = ug * 12;
    const int rs = lane & 15;             // row slot 0..15
    const long row0 = (long)blockIdx.x * 512 + (long)wv * 128 + (long)rs * 8;
    const float* xb = x + row0 * D_;

    float acc[8][12];
#pragma unroll
    for (int r = 0; r < 8; ++r)
#pragma unroll
        for (int j = 0; j < 12; ++j) acc[r][j] = 0.0f;

#pragma unroll 1
    for (int d4 = 0; d4 < D_ / 4; ++d4) {            // 64 float4 chunks of d
        float4 xv[8];
#pragma unroll
        for (int r = 0; r < 8; ++r)
            xv[r] = *(const float4*)(xb + r * D_ + d4 * 4);
#pragma unroll
        for (int c = 0; c < 4; ++c) {
            const float4* kp = (const float4*)&K[(d4 * 4 + c) * U_ + u0];
            const float4 k0 = kp[0];                 // 3x ds_read_b128,
            const float4 k1 = kp[1];                 // conflict-free (disjoint
            const float4 k2 = kp[2];                 // banks per ugroup)
#pragma unroll
            for (int r = 0; r < 8; ++r) {
                const float s = (c == 0) ? xv[r].x : (c == 1) ? xv[r].y
                              : (c == 2) ? xv[r].z : xv[r].w;
                acc[r][0]  += s * k0.x;  acc[r][1]  += s * k0.y;
                acc[r][2]  += s * k0.z;  acc[r][3]  += s * k0.w;
                acc[r][4]  += s * k1.x;  acc[r][5]  += s * k1.y;
                acc[r][6]  += s * k1.z;  acc[r][7]  += s * k1.w;
                acc[r][8]  += s * k2.x;  acc[r][9]  += s * k2.y;
                acc[r][10] += s * k2.z;  acc[r][11] += s * k2.w;
            }
        }
    }

    const float b0 = bsh[u0+0], b1 = bsh[u0+1], b2  = bsh[u0+2],  b3  = bsh[u0+3];
    const float b4 = bsh[u0+4], b5 = bsh[u0+5], b6  = bsh[u0+6],  b7  = bsh[u0+7];
    const float b8 = bsh[u0+8], b9 = bsh[u0+9], b10 = bsh[u0+10], b11 = bsh[u0+11];
#pragma unroll
    for (int r = 0; r < 8; ++r) {
        float4* op = (float4*)(logits + (row0 + r) * U_ + u0);   // 16B aligned
        float4 v0, v1, v2;
        v0.x = acc[r][0] + b0;   v0.y = acc[r][1] + b1;
        v0.z = acc[r][2] + b2;   v0.w = acc[r][3] + b3;
        v1.x = acc[r][4] + b4;   v1.y = acc[r][5] + b5;
        v1.z = acc[r][6] + b6;   v1.w = acc[r][7] + b7;
        v2.x = acc[r][8] + b8;   v2.y = acc[r][9] + b9;
        v2.z = acc[r][10] + b10; v2.w = acc[r][11] + b11;
        op[0] = v0; op[1] = v1; op[2] = v2;
    }
}

// ---------------------------------------------------------------------------
// Max-plus body (R2-measured best: 215.5 µs): LDS broadcast (12x ds_read_b128
// uniform) + 24x v_pk_add_f32 + 24x v_max3_f32 tree. Exact. UNTOUCHED.
// ---------------------------------------------------------------------------
__device__ __forceinline__ float step_max_lds(const float4* sb, const v2f* tc2) {
    float4 s[12];
#pragma unroll
    for (int k = 0; k < 12; ++k) s[k] = sb[k];        // 12x ds_read_b128
    float cf[48];
#pragma unroll
    for (int k = 0; k < 12; ++k) {
        v2f lo, hi;
        lo.x = s[k].x; lo.y = s[k].y;
        hi.x = s[k].z; hi.y = s[k].w;
        v2f r0 = pk_add(lo, tc2[2 * k + 0]);
        v2f r1 = pk_add(hi, tc2[2 * k + 1]);
        cf[4*k+0] = r0.x; cf[4*k+1] = r0.y;
        cf[4*k+2] = r1.x; cf[4*k+3] = r1.y;
    }
    float t1[16];
#pragma unroll
    for (int i = 0; i < 16; ++i) t1[i] = max3f(cf[3*i], cf[3*i+1], cf[3*i+2]);
    float t2[6];
#pragma unroll
    for (int i = 0; i < 5; ++i) t2[i] = max3f(t1[3*i], t1[3*i+1], t1[3*i+2]);
    t2[5] = t1[15];
    const float a = max3f(t2[0], t2[1], t2[2]);
    const float b = max3f(t2[3], t2[4], t2[5]);
    return fmaxf(a, b);
}

// ---------------------------------------------------------------------------
// K2: Viterbi forward (R2/R6 structure verbatim — 215.4 µs measured).
// ---------------------------------------------------------------------------
__global__ __launch_bounds__(64, 1) void k_forward(const float* __restrict__ trans,
                                                   const float* __restrict__ logits,
                                                   float* __restrict__ delta) {
    __shared__ float4 sbuf[2][U_ / 4];    // parity double buffer, 2x48 floats
    const int lane = threadIdx.x;
    const int b = blockIdx.x;
    const int u = (lane < U_) ? lane : (U_ - 1);

    v2f tc2[U_ / 2];
#pragma unroll
    for (int v = 0; v < U_; v += 2) {
        tc2[v / 2].x = trans[v * U_ + u];
        tc2[v / 2].y = trans[(v + 1) * U_ + u];
    }

    const float* lin = logits + (long)b * T_ * U_;
    float* dout = delta + (long)b * T_ * U_;

    float state = lin[u];                 // delta_0 = logits row 0
    dout[u] = state;                      // dup-writes (lanes 48-63) benign
    ((float*)sbuf[0])[u] = state;         // t=0 parity 0

    float pf[8];
#pragma unroll
    for (int i = 0; i < 8; ++i) pf[i] = lin[(1 + i) * U_ + u];  // rows 1..8

    const float* lp = lin + 9 * U_ + u;   // prefetch base: row tb+8 for tb=1
    float* dp = dout + 1 * U_ + u;        // store base: row tb

#pragma unroll 1
    for (int g = 0; g < 127; ++g) {       // t = 1+8g .. 8+8g  (1..1016)
#pragma unroll
        for (int j = 0; j < 8; ++j) {
            const float logit = pf[j];
            pf[j] = lp[j * U_];                       // imm offset j*192 B

            const float4* sb = sbuf[j & 1];           // parity (t-1)&1 == j&1
            const float m = step_max_lds(sb, tc2);
            state = logit + m;                        // exact ref op order
            ((float*)sbuf[(j & 1) ^ 1])[u] = state;
            dp[j * U_] = state;                       // imm offset j*192 B
        }
        lp += 8 * U_;
        dp += 8 * U_;
    }

    // tail: t = 1017..1023 (7 steps); pf[0..6] hold rows 1017..1023
#pragma unroll
    for (int j = 0; j < 7; ++j) {
        const float logit = pf[j];
        const float4* sb = sbuf[j & 1];               // (t-1)=1016+j parity j&1
        const float m = step_max_lds(sb, tc2);
        state = logit + m;
        ((float*)sbuf[(j & 1) ^ 1])[u] = state;
        dp[j * U_] = state;
    }
}

// Fallback (in-place) variant if ws can't fit a second delta buffer.
__global__ __launch_bounds__(64, 1) void k_forward_inplace(const float* __restrict__ trans,
                                                           float* __restrict__ delta) {
    __shared__ float4 sbuf[2][U_ / 4];
    const int lane = threadIdx.x;
    const int b = blockIdx.x;
    const int u = (lane < U_) ? lane : (U_ - 1);

    v2f tc2[U_ / 2];
#pragma unroll
    for (int v = 0; v < U_; v += 2) {
        tc2[v / 2].x = trans[v * U_ + u];
        tc2[v / 2].y = trans[(v + 1) * U_ + u];
    }

    float* base = delta + (long)b * T_ * U_;
    float state = base[u];
    ((float*)sbuf[0])[u] = state;

#pragma unroll 1
    for (int t = 1; t < T_; ++t) {
        const float logit = base[(long)t * U_ + u];
        const float m = step_max_lds(sbuf[(t - 1) & 1], tc2);
        state = logit + m;
        ((float*)sbuf[t & 1])[u] = state;
        base[(long)t * U_ + u] = state;
    }
}

// ---------------------------------------------------------------------------
// K3: backpointers (R6-measured form, reverted). Throughput-parallel.
// ---------------------------------------------------------------------------
#define BP_ROWS 32
__global__ __launch_bounds__(64, 1) void k_bp(const float* __restrict__ trans,
                                              const float* __restrict__ delta,
                                              unsigned char* __restrict__ bp) {
    __shared__ float sbuf[2][U_];         // row parity double buffer
    const int lane = threadIdx.x;
    const int u = (lane < U_) ? lane : (U_ - 1);

    float tc[U_];
#pragma unroll
    for (int v = 0; v < U_; ++v) tc[v] = trans[v * U_ + u];

    const int NROW = B_ * (T_ - 1);       // 130944
    const int row0 = blockIdx.x * BP_ROWS;
    if (row0 >= NROW) return;

    int b = row0 / (T_ - 1);              // uniform, once per block
    int tm1 = row0 - b * (T_ - 1);        // (t-1) in 0..1022

    float dval = delta[((long)b * T_ + tm1) * U_ + u];   // prefetch row0

#pragma unroll 1
    for (int i = 0; i < BP_ROWS; ++i) {
        const int row = row0 + i;
        if (row >= NROW) break;           // uniform guard

        sbuf[i & 1][u] = dval;            // stage current row (dup benign)

        // advance cursor, prefetch next row
        int bn = b, tn = tm1 + 1;
        if (tn == T_ - 1) { tn = 0; bn = b + 1; }
        float dnext = 0.0f;
        if (row + 1 < NROW) dnext = delta[((long)bn * T_ + tn) * U_ + u];

        const float4* sb4 = (const float4*)sbuf[i & 1];
        float best = -3.4e38f;
        int bi = 0;
#pragma unroll
        for (int k = 0; k < U_ / 4; ++k) {
            float4 s = sb4[k];            // uniform broadcast read
            float c0 = s.x + tc[4*k+0];
            float c1 = s.y + tc[4*k+1];
            float c2 = s.z + tc[4*k+2];
            float c3 = s.w + tc[4*k+3];
            bi = (c0 > best) ? 4*k+0 : bi;  best = fmaxf(best, c0);
            bi = (c1 > best) ? 4*k+1 : bi;  best = fmaxf(best, c1);
            bi = (c2 > best) ? 4*k+2 : bi;  best = fmaxf(best, c2);
            bi = (c3 > best) ? 4*k+3 : bi;  best = fmaxf(best, c3);
        }
        bp[(long)row * U_ + u] = (unsigned char)bi;   // dup-writes benign

        b = bn; tm1 = tn; dval = dnext;
    }
}

// ---------------------------------------------------------------------------
// K4: backtrace (R6 blocked composition, verbatim — verified).
// ---------------------------------------------------------------------------
#define KB_ 32
#define NB_ 32
__global__ __launch_bounds__(256) void k_back(const float* __restrict__ delta,
                                              const unsigned char* __restrict__ bp,
                                              float* __restrict__ out) {
    __shared__ unsigned char bpl[1024 * U_];      // 49152 B (row 1023 = identity)
    __shared__ unsigned char gmap[NB_ * U_];      // 1536 B: gmap[i][e] = exit tag
    __shared__ unsigned char eIn[NB_];            // entry tag per block
    __shared__ float tags[T_];                    // 4 KB
    __shared__ int Ash;
    const int tid = threadIdx.x;
    const int b = blockIdx.x;

    // stage bp rows 0..1022 (12276 dwords), identity row 1023
    const uint32_t* src = (const uint32_t*)(bp + (long)b * (T_ - 1) * U_);
    uint32_t* dst = (uint32_t*)bpl;
    const int NW = (T_ - 1) * U_ / 4;             // 12276
    for (int i = tid; i < NW; i += 256) dst[i] = src[i];
    if (tid < U_) bpl[1023 * U_ + tid] = (unsigned char)tid;

    // wave-parallel argmax of final delta row (first wave only)
    if (tid < 64) {
        const int lane = tid;
        float v = (lane < U_) ? delta[((long)b * T_ + (T_ - 1)) * U_ + lane] : -3.4e38f;
        int idx = (lane < U_) ? lane : 64;
#pragma unroll
        for (int off = 32; off >= 1; off >>= 1) {
            const float ov = __shfl_xor(v, off);
            const int oi = __shfl_xor(idx, off);
            if (ov > v || (ov == v && oi < idx)) { v = ov; idx = oi; }
        }
        if (lane == 0) Ash = idx;
    }
    __syncthreads();

    // Phase A: 1536 tasks = 6 chains/thread, hop-major interleave.
    int ik[6], ek[6], ck[6];
#pragma unroll
    for (int k = 0; k < 6; ++k) {
        const int tau = tid + k * 256;
        ik[k] = tau / U_;                 // block 0..31
        ek[k] = tau - ik[k] * U_;         // entry tag 0..47
        ck[k] = ek[k];
    }
#pragma unroll
    for (int h = 0; h < KB_; ++h) {
#pragma unroll
        for (int k = 0; k < 6; ++k) {
            const int r = ik[k] * KB_ + (KB_ - 1 - h);   // hi down to lo
            ck[k] = bpl[r * U_ + ck[k]];
        }
    }
#pragma unroll
    for (int k = 0; k < 6; ++k) gmap[ik[k] * U_ + ek[k]] = (unsigned char)ck[k];
    __syncthreads();

    // Phase B: serial composition over block maps (31 dependent LDS reads).
    if (tid == 0) {
        int cur = Ash;
        eIn[NB_ - 1] = (unsigned char)cur;
#pragma unroll 1
        for (int i = NB_ - 1; i >= 1; --i) {
            cur = gmap[i * U_ + cur];
            eIn[i - 1] = (unsigned char)cur;
        }
    }
    __syncthreads();

    // Phase C: 32 parallel re-chases with known entry tags, emit all tags.
    if (tid < NB_) {
        const int i = tid;
        int cur = eIn[i];
#pragma unroll
        for (int h = 0; h < KB_; ++h) {
            const int r = i * KB_ + (KB_ - 1 - h);
            cur = bpl[r * U_ + cur];
            tags[r] = (float)cur;
        }
    }
    __syncthreads();

    float* o = out + (long)b * T_;
    for (int i = tid; i < T_; i += 256) o[i] = tags[i];
}

// ---------------------------------------------------------------------------
extern "C" void kernel_launch(void* const* d_in, const int* in_sizes, int n_in,
                              void* d_out, int out_size, void* d_ws, size_t ws_size,
                              hipStream_t stream) {
    const float* x     = (const float*)d_in[0];   // (B,T,D)
    const float* kern  = (const float*)d_in[1];   // (D,U)
    const float* bias  = (const float*)d_in[2];   // (U,)
    const float* trans = (const float*)d_in[3];   // (U,U)
    float* out = (float*)d_out;                   // (B,T) fp32 tags

    const size_t NBT = (size_t)B_ * T_ * U_ * sizeof(float);  // 25,165,824 B

    float* logits = (float*)d_ws;
    const bool two_buf = ws_size >= 2 * NBT + (size_t)B_ * T_ * U_;
    float* delta = two_buf ? (float*)((char*)d_ws + NBT) : logits;
    unsigned char* bp = (unsigned char*)d_ws + (two_buf ? 2 * NBT : NBT);

    const int NROW = B_ * (T_ - 1);
    const int bp_grid = (NROW + BP_ROWS - 1) / BP_ROWS;   // 4092

    k_logits<<<B_ * T_ / 512, 256, 0, stream>>>(x, kern, bias, logits);
    if (two_buf)
        k_forward<<<B_, 64, 0, stream>>>(trans, logits, delta);
    else
        k_forward_inplace<<<B_, 64, 0, stream>>>(trans, logits);
    k_bp  <<<bp_grid, 64, 0, stream>>>(trans, delta, bp);
    k_back<<<B_, 256, 0, stream>>>(delta, bp, out);
}